// Round 1
// baseline (557.601 us; speedup 1.0000x reference)
//
#include <hip/hip_runtime.h>
#include <math.h>

#define LQ 40000
#define DMODEL 256
#define NHD 8
#define NPT 4
#define DHD 32
#define HSP 200
#define WSP 200

// C[M x N] = (A [+ A2]) @ Wt^T + bias   (K = 256 fixed)
// Row j of the (virtual) weight matrix:
//   j <  split : W1[j]      , bias b1[j]
//   j >= split : W2[j-split], bias b2[j-split]
// TM = 64, TK = 16, block = 256 threads, micro-tile 4 x (TN/16) per thread.
template <int TN>
__global__ __launch_bounds__(256) void gemm_nt_kernel(
    const float* __restrict__ A, const float* __restrict__ A2,
    const float* __restrict__ W1, const float* __restrict__ b1,
    const float* __restrict__ W2, const float* __restrict__ b2,
    int split, float* __restrict__ C, int N)
{
    constexpr int TM = 64;
    constexpr int TK = 16;
    __shared__ float As[TK][TM + 1];
    __shared__ float Bs[TK][TN + 1];

    const int tid = threadIdx.x;
    const int tx = tid & 15;
    const int ty = tid >> 4;
    const int rowBase = blockIdx.x * TM;
    const int colBase = blockIdx.y * TN;

    float acc[4][TN / 16];
#pragma unroll
    for (int i = 0; i < 4; ++i)
#pragma unroll
        for (int j = 0; j < TN / 16; ++j) acc[i][j] = 0.f;

    for (int k0 = 0; k0 < 256; k0 += TK) {
        // A tile: TM*TK = 1024 elems, 4 per thread
#pragma unroll
        for (int r = 0; r < (TM * TK) / 256; ++r) {
            int l = tid + 256 * r;
            int m = l >> 4, k = l & 15;
            size_t idx = (size_t)(rowBase + m) * 256 + (k0 + k);
            float v = A[idx];
            if (A2) v += A2[idx];
            As[k][m] = v;
        }
        // B tile: TN*TK elems
#pragma unroll
        for (int r = 0; r < (TN * TK) / 256; ++r) {
            int l = tid + 256 * r;
            int n = l >> 4, k = l & 15;
            int col = colBase + n;
            const float* Wp = (col < split) ? (W1 + (size_t)col * 256)
                                            : (W2 + (size_t)(col - split) * 256);
            Bs[k][n] = Wp[k0 + k];
        }
        __syncthreads();
#pragma unroll
        for (int k = 0; k < TK; ++k) {
            float a[4], b[TN / 16];
#pragma unroll
            for (int i = 0; i < 4; ++i) a[i] = As[k][ty + 16 * i];
#pragma unroll
            for (int j = 0; j < TN / 16; ++j) b[j] = Bs[k][tx + 16 * j];
#pragma unroll
            for (int i = 0; i < 4; ++i)
#pragma unroll
                for (int j = 0; j < TN / 16; ++j) acc[i][j] += a[i] * b[j];
        }
        __syncthreads();
    }

#pragma unroll
    for (int j = 0; j < TN / 16; ++j) {
        int col = colBase + tx + 16 * j;
        float bb = (col < split) ? b1[col] : b2[col - split];
#pragma unroll
        for (int i = 0; i < 4; ++i) {
            int row = rowBase + ty + 16 * i;
            C[(size_t)row * N + col] = acc[i][j] + bb;
        }
    }
}

// One block per query; 8 groups of 32 lanes, group g = head h, lane = channel d.
// raw[q][0..63]  = sampling offsets (h*8 + p*2 + {x,y})
// raw[q][64..95] = attention logits (h*4 + p)
__global__ __launch_bounds__(256) void sample_kernel(
    const float* __restrict__ raw, const float* __restrict__ rp,
    const float* __restrict__ value, float* __restrict__ outa)
{
    const int q = blockIdx.x;
    const int h = threadIdx.x >> 5;
    const int d = threadIdx.x & 31;
    const float* r = raw + (size_t)q * 96;

    // softmax over the 4 points of this head (uniform across the 32 lanes)
    float l0 = r[64 + h * 4 + 0];
    float l1 = r[64 + h * 4 + 1];
    float l2 = r[64 + h * 4 + 2];
    float l3 = r[64 + h * 4 + 3];
    float mx = fmaxf(fmaxf(l0, l1), fmaxf(l2, l3));
    float e0 = expf(l0 - mx), e1 = expf(l1 - mx), e2 = expf(l2 - mx), e3 = expf(l3 - mx);
    float inv = 1.f / (e0 + e1 + e2 + e3);
    float wt[4] = {e0 * inv, e1 * inv, e2 * inv, e3 * inv};

    // x = (refx + ox/W)*W - 0.5 = refx*W + ox - 0.5
    float bx = rp[(size_t)q * 2 + 0] * (float)WSP - 0.5f;
    float by = rp[(size_t)q * 2 + 1] * (float)HSP - 0.5f;

    const float* vh = value + (size_t)h * DHD + d;  // value[i*256 + h*32 + d]
    float acc = 0.f;
#pragma unroll
    for (int p = 0; p < 4; ++p) {
        float x = bx + r[h * 8 + p * 2 + 0];
        float y = by + r[h * 8 + p * 2 + 1];
        float x0f = floorf(x), y0f = floorf(y);
        int x0 = (int)x0f, y0 = (int)y0f;
        float lw = x - x0f, lh = y - y0f;
        float hw = 1.f - lw, hh = 1.f - lh;
        float v = 0.f;
        if (x0 >= 0 && x0 < WSP && y0 >= 0 && y0 < HSP)
            v += hh * hw * vh[(size_t)(y0 * WSP + x0) * DMODEL];
        if (x0 + 1 >= 0 && x0 + 1 < WSP && y0 >= 0 && y0 < HSP)
            v += hh * lw * vh[(size_t)(y0 * WSP + x0 + 1) * DMODEL];
        if (x0 >= 0 && x0 < WSP && y0 + 1 >= 0 && y0 + 1 < HSP)
            v += lh * hw * vh[(size_t)((y0 + 1) * WSP + x0) * DMODEL];
        if (x0 + 1 >= 0 && x0 + 1 < WSP && y0 + 1 >= 0 && y0 + 1 < HSP)
            v += lh * lw * vh[(size_t)((y0 + 1) * WSP + x0 + 1) * DMODEL];
        acc += wt[p] * v;
    }
    outa[(size_t)q * DMODEL + h * DHD + d] = acc;
}

extern "C" void kernel_launch(void* const* d_in, const int* in_sizes, int n_in,
                              void* d_out, int out_size, void* d_ws, size_t ws_size,
                              hipStream_t stream)
{
    const float* query         = (const float*)d_in[0];
    const float* query_pos     = (const float*)d_in[1];
    const float* ref_points    = (const float*)d_in[2];
    const float* input_flatten = (const float*)d_in[3];
    const float* W_value       = (const float*)d_in[4];
    const float* b_value       = (const float*)d_in[5];
    const float* W_off         = (const float*)d_in[6];
    const float* b_off         = (const float*)d_in[7];
    const float* W_attn        = (const float*)d_in[8];
    const float* b_attn        = (const float*)d_in[9];
    const float* W_out         = (const float*)d_in[10];
    const float* b_out         = (const float*)d_in[11];
    float* out = (float*)d_out;

    float* ws   = (float*)d_ws;
    float* val  = ws;                               // LQ*256 floats (41 MB)
    float* raw  = val + (size_t)LQ * DMODEL;        // LQ*96  floats (15 MB)
    float* outa = raw + (size_t)LQ * 96;            // LQ*256 floats (41 MB)

    dim3 blk(256);

    // 1) value = input_flatten @ W_value^T + b_value
    gemm_nt_kernel<64><<<dim3(LQ / 64, DMODEL / 64), blk, 0, stream>>>(
        input_flatten, nullptr, W_value, b_value, nullptr, nullptr, DMODEL, val, DMODEL);

    // 2) raw = (query + query_pos) @ [W_off; W_attn]^T + [b_off; b_attn]
    gemm_nt_kernel<96><<<dim3(LQ / 64, 1), blk, 0, stream>>>(
        query, query_pos, W_off, b_off, W_attn, b_attn, 64, raw, 96);

    // 3) softmax + bilinear sampling + point-weighted sum
    sample_kernel<<<dim3(LQ), blk, 0, stream>>>(raw, ref_points, val, outa);

    // 4) out = outa @ W_out^T + b_out
    gemm_nt_kernel<64><<<dim3(LQ / 64, DMODEL / 64), blk, 0, stream>>>(
        outa, nullptr, W_out, b_out, nullptr, nullptr, DMODEL, out, DMODEL);
}

// Round 2
// 286.997 us; speedup vs baseline: 1.9429x; 1.9429x over previous
//
#include <hip/hip_runtime.h>
#include <math.h>

#define LQ 40000
#define DMODEL 256
#define NHD 8
#define NPT 4
#define DHD 32
#define HSP 200
#define WSP 200

typedef short s16x8 __attribute__((ext_vector_type(8)));
typedef float f32x4 __attribute__((ext_vector_type(4)));

__device__ __forceinline__ unsigned short f2b(float f) {
    unsigned u = __builtin_bit_cast(unsigned, f);
    u += 0x7FFFu + ((u >> 16) & 1u);   // round-to-nearest-even
    return (unsigned short)(u >> 16);
}
__device__ __forceinline__ float b2f(unsigned short u) {
    return __builtin_bit_cast(float, ((unsigned)u) << 16);
}

// ---------------------------------------------------------------------------
// bf16 MFMA GEMM: C[M x ncols] = (A [+ A2]) @ W^T + bias, K = 256 fixed.
// W row j: j < split -> W1[j]/b1[j], else W2[j-split]/b2[j-split]. Weights fp32.
// Block 256 thr (4 waves), tile 64(M) x 64(N), full K=256 staged in LDS once.
// LDS rows padded to 264 bf16 (528 B => 2-way bank alias only, free).
// A-frag: A[m=lane&15][k=quad*8+j]; B-frag: B_n[n=lane&15][k=quad*8+j];
// C/D: col=lane&15, row=quad*4+reg.
// ---------------------------------------------------------------------------
template <typename AT, typename CT, bool HasA2>
__global__ __launch_bounds__(256) void gemm_mfma(
    const AT* __restrict__ A, const float* __restrict__ A2,
    const float* __restrict__ W1, const float* __restrict__ b1,
    const float* __restrict__ W2, const float* __restrict__ b2,
    int split, int ncols, CT* __restrict__ C, int ldC)
{
    constexpr int LDA = 264;                     // bf16 elems per LDS row
    __shared__ __align__(16) unsigned short Asm[64 * LDA];
    __shared__ __align__(16) unsigned short Bsm[64 * LDA];

    const int t = threadIdx.x;
    const int rowBase = blockIdx.x * 64;
    const int colBase = blockIdx.y * 64;

    // ---- stage A tile (64 rows x 256 k) ----
#pragma unroll
    for (int rep = 0; rep < 8; ++rep) {
        int f8 = t + 256 * rep;                  // index of 8-element group
        int row = f8 >> 5;                       // 0..63
        int c8 = f8 & 31;                        // 0..31 (k-group of 8)
        unsigned short* dst = &Asm[row * LDA + c8 * 8];
        if constexpr (sizeof(AT) == 4) {
            const float* Ap = (const float*)A + (size_t)(rowBase + row) * 256 + c8 * 8;
            float4 v0 = *(const float4*)Ap;
            float4 v1 = *(const float4*)(Ap + 4);
            if constexpr (HasA2) {
                const float* Bp = A2 + (size_t)(rowBase + row) * 256 + c8 * 8;
                float4 w0 = *(const float4*)Bp;
                float4 w1 = *(const float4*)(Bp + 4);
                v0.x += w0.x; v0.y += w0.y; v0.z += w0.z; v0.w += w0.w;
                v1.x += w1.x; v1.y += w1.y; v1.z += w1.z; v1.w += w1.w;
            }
            union { unsigned short u[8]; uint4 v; } tmp;
            tmp.u[0] = f2b(v0.x); tmp.u[1] = f2b(v0.y);
            tmp.u[2] = f2b(v0.z); tmp.u[3] = f2b(v0.w);
            tmp.u[4] = f2b(v1.x); tmp.u[5] = f2b(v1.y);
            tmp.u[6] = f2b(v1.z); tmp.u[7] = f2b(v1.w);
            *(uint4*)dst = tmp.v;
        } else {
            const unsigned short* Ap =
                (const unsigned short*)A + (size_t)(rowBase + row) * 256 + c8 * 8;
            *(uint4*)dst = *(const uint4*)Ap;
        }
    }

    // ---- stage B tile (64 weight rows x 256 k), clamp row for ragged N ----
#pragma unroll
    for (int rep = 0; rep < 8; ++rep) {
        int f8 = t + 256 * rep;
        int row = f8 >> 5;
        int c8 = f8 & 31;
        int n = colBase + row;
        int nc = n < ncols ? n : (ncols - 1);
        const float* Wp = (nc < split) ? (W1 + (size_t)nc * 256)
                                       : (W2 + (size_t)(nc - split) * 256);
        float4 v0 = *(const float4*)(Wp + c8 * 8);
        float4 v1 = *(const float4*)(Wp + c8 * 8 + 4);
        union { unsigned short u[8]; uint4 v; } tmp;
        tmp.u[0] = f2b(v0.x); tmp.u[1] = f2b(v0.y);
        tmp.u[2] = f2b(v0.z); tmp.u[3] = f2b(v0.w);
        tmp.u[4] = f2b(v1.x); tmp.u[5] = f2b(v1.y);
        tmp.u[6] = f2b(v1.z); tmp.u[7] = f2b(v1.w);
        *(uint4*)&Bsm[row * LDA + c8 * 8] = tmp.v;
    }

    __syncthreads();

    // ---- MFMA: wave w owns cols [w*16, w*16+16), all 64 rows ----
    const int wave = t >> 6;
    const int lane = t & 63;
    const int l15 = lane & 15;
    const int quad = lane >> 4;

    f32x4 acc[4];
#pragma unroll
    for (int m = 0; m < 4; ++m) acc[m] = (f32x4){0.f, 0.f, 0.f, 0.f};

#pragma unroll
    for (int ks = 0; ks < 8; ++ks) {
        s16x8 bfrag = *(const s16x8*)&Bsm[(wave * 16 + l15) * LDA + ks * 32 + quad * 8];
#pragma unroll
        for (int m = 0; m < 4; ++m) {
            s16x8 afrag = *(const s16x8*)&Asm[(m * 16 + l15) * LDA + ks * 32 + quad * 8];
            acc[m] = __builtin_amdgcn_mfma_f32_16x16x32_bf16(afrag, bfrag, acc[m], 0, 0, 0);
        }
    }

    // ---- epilogue ----
    const int col = colBase + wave * 16 + l15;
    if (col < ncols) {
        float bb = (col < split) ? b1[col] : b2[col - split];
#pragma unroll
        for (int m = 0; m < 4; ++m)
#pragma unroll
            for (int r2 = 0; r2 < 4; ++r2) {
                int row = rowBase + m * 16 + quad * 4 + r2;
                float v = acc[m][r2] + bb;
                if constexpr (sizeof(CT) == 2)
                    C[(size_t)row * ldC + col] = (CT)f2b(v);
                else
                    C[(size_t)row * ldC + col] = (CT)v;
            }
    }
}

// ---------------------------------------------------------------------------
// Deformable sampling. Block = 256 thr, 8 queries per block.
// Phase 1: thread (qi,h,p) computes fused corner weights (softmax * bilinear *
//          validity) and clamped element indices once into LDS.
// Phase 2: thread (h,d) loops the 8 queries, 16 branchless bf16 gathers each.
// ---------------------------------------------------------------------------
__global__ __launch_bounds__(256) void sample_kernel(
    const float* __restrict__ raw, const float* __restrict__ rp,
    const unsigned short* __restrict__ value, unsigned short* __restrict__ outa)
{
    __shared__ int4   sIdx[8][8][4];
    __shared__ float4 sW[8][8][4];

    const int t = threadIdx.x;
    {   // phase 1
        const int qi = t >> 5, h = (t >> 2) & 7, p = t & 3;
        const int q = blockIdx.x * 8 + qi;
        const float* r = raw + (size_t)q * 96;
        float l0 = r[64 + h * 4 + 0], l1 = r[64 + h * 4 + 1];
        float l2 = r[64 + h * 4 + 2], l3 = r[64 + h * 4 + 3];
        float mx = fmaxf(fmaxf(l0, l1), fmaxf(l2, l3));
        float e0 = __expf(l0 - mx), e1 = __expf(l1 - mx);
        float e2 = __expf(l2 - mx), e3 = __expf(l3 - mx);
        float inv = 1.f / (e0 + e1 + e2 + e3);
        float ep = (p == 0) ? e0 : (p == 1) ? e1 : (p == 2) ? e2 : e3;
        float wp = ep * inv;

        float x = rp[(size_t)q * 2 + 0] * (float)WSP - 0.5f + r[h * 8 + p * 2 + 0];
        float y = rp[(size_t)q * 2 + 1] * (float)HSP - 0.5f + r[h * 8 + p * 2 + 1];
        float x0f = floorf(x), y0f = floorf(y);
        int x0 = (int)x0f, y0 = (int)y0f;
        float lw = x - x0f, lh = y - y0f;
        float cw[4] = {(1.f - lh) * (1.f - lw), (1.f - lh) * lw,
                       lh * (1.f - lw), lh * lw};
        int4 I; float4 W;
        int* Ip = &I.x; float* Wp = &W.x;
#pragma unroll
        for (int c = 0; c < 4; ++c) {
            int cx = x0 + (c & 1), cy = y0 + (c >> 1);
            bool valid = (cx >= 0) & (cx < WSP) & (cy >= 0) & (cy < HSP);
            int ccx = cx < 0 ? 0 : (cx > WSP - 1 ? WSP - 1 : cx);
            int ccy = cy < 0 ? 0 : (cy > HSP - 1 ? HSP - 1 : cy);
            Ip[c] = (ccy * WSP + ccx) * DMODEL + h * DHD;
            Wp[c] = valid ? cw[c] * wp : 0.f;
        }
        sIdx[qi][h][p] = I;
        sW[qi][h][p] = W;
    }
    __syncthreads();

    // phase 2
    const int h = t >> 5, d = t & 31;
    for (int qi = 0; qi < 8; ++qi) {
        float acc = 0.f;
#pragma unroll
        for (int p = 0; p < 4; ++p) {
            int4 I = sIdx[qi][h][p];
            float4 W = sW[qi][h][p];
            acc += W.x * b2f(value[I.x + d]);
            acc += W.y * b2f(value[I.y + d]);
            acc += W.z * b2f(value[I.z + d]);
            acc += W.w * b2f(value[I.w + d]);
        }
        int q = blockIdx.x * 8 + qi;
        outa[(size_t)q * DMODEL + h * DHD + d] = f2b(acc);
    }
}

extern "C" void kernel_launch(void* const* d_in, const int* in_sizes, int n_in,
                              void* d_out, int out_size, void* d_ws, size_t ws_size,
                              hipStream_t stream)
{
    const float* query         = (const float*)d_in[0];
    const float* query_pos     = (const float*)d_in[1];
    const float* ref_points    = (const float*)d_in[2];
    const float* input_flatten = (const float*)d_in[3];
    const float* W_value       = (const float*)d_in[4];
    const float* b_value       = (const float*)d_in[5];
    const float* W_off         = (const float*)d_in[6];
    const float* b_off         = (const float*)d_in[7];
    const float* W_attn        = (const float*)d_in[8];
    const float* b_attn        = (const float*)d_in[9];
    const float* W_out         = (const float*)d_in[10];
    const float* b_out         = (const float*)d_in[11];
    float* out = (float*)d_out;

    unsigned short* val  = (unsigned short*)d_ws;                 // LQ*256 bf16
    float*          raw  = (float*)(val + (size_t)LQ * DMODEL);   // LQ*96 fp32
    unsigned short* outa = (unsigned short*)(raw + (size_t)LQ * 96); // LQ*256 bf16

    dim3 blk(256);

    // 1) val(bf16) = input_flatten @ W_value^T + b_value
    gemm_mfma<float, unsigned short, false><<<dim3(LQ / 64, 4), blk, 0, stream>>>(
        input_flatten, nullptr, W_value, b_value, W_value, b_value, 256, 256,
        val, DMODEL);

    // 2) raw = (query + query_pos) @ [W_off; W_attn]^T + [b_off; b_attn]
    gemm_mfma<float, float, true><<<dim3(LQ / 64, 2), blk, 0, stream>>>(
        query, query_pos, W_off, b_off, W_attn, b_attn, 64, 96, raw, 96);

    // 3) softmax + bilinear sampling + point-weighted sum -> outa (bf16)
    sample_kernel<<<dim3(LQ / 8), blk, 0, stream>>>(raw, ref_points, val, outa);

    // 4) out = outa @ W_out^T + b_out
    gemm_mfma<unsigned short, float, false><<<dim3(LQ / 64, 4), blk, 0, stream>>>(
        outa, nullptr, W_out, b_out, W_out, b_out, 256, 256, out, DMODEL);
}

// Round 3
// 281.883 us; speedup vs baseline: 1.9781x; 1.0181x over previous
//
#include <hip/hip_runtime.h>
#include <math.h>

#define LQ 40000
#define DMODEL 256
#define NHD 8
#define NPT 4
#define DHD 32
#define HSP 200
#define WSP 200

typedef short s16x8 __attribute__((ext_vector_type(8)));
typedef float f32x4 __attribute__((ext_vector_type(4)));

__device__ __forceinline__ unsigned short f2b(float f) {
    unsigned u = __builtin_bit_cast(unsigned, f);
    u += 0x7FFFu + ((u >> 16) & 1u);   // round-to-nearest-even
    return (unsigned short)(u >> 16);
}
__device__ __forceinline__ float b2f(unsigned short u) {
    return __builtin_bit_cast(float, ((unsigned)u) << 16);
}

// ---------------------------------------------------------------------------
// Convert the 4 fp32 weight matrices to bf16 in workspace (one-shot, tiny).
// Layout: [W_value 65536][W_off 16384][W_attn 8192][W_out 65536]
// ---------------------------------------------------------------------------
__global__ __launch_bounds__(256) void convert_weights(
    const float* __restrict__ s0, const float* __restrict__ s1,
    const float* __restrict__ s2, const float* __restrict__ s3,
    unsigned short* __restrict__ dst)
{
    int i4 = (blockIdx.x * 256 + threadIdx.x) * 4;
    const float* src;
    int base;
    if (i4 < 65536)       { src = s0; base = 0; }
    else if (i4 < 81920)  { src = s1; base = 65536; }
    else if (i4 < 90112)  { src = s2; base = 81920; }
    else                  { src = s3; base = 90112; }
    float4 v = *(const float4*)(src + (i4 - base));
    union { unsigned short u[4]; uint2 q; } tmp;
    tmp.u[0] = f2b(v.x); tmp.u[1] = f2b(v.y);
    tmp.u[2] = f2b(v.z); tmp.u[3] = f2b(v.w);
    *(uint2*)(dst + i4) = tmp.q;
}

// ---------------------------------------------------------------------------
// bf16 MFMA GEMM, full-N per block: C[64 x NCOLS] per block, K=256.
// A read exactly once (fp32 [+A2] converted, or bf16 copied); W is bf16
// (preconverted) and L2-resident. TK=64 K-loop, single-buffered LDS.
// Wave w owns n-tiles {w, w+4, w+8, w+12} (16-col tiles); tiles >= NT masked.
// C/D frag: col=lane&15, row=quad*4+reg.
// ---------------------------------------------------------------------------
template <int NCOLS, typename AT, typename CT, bool HasA2>
__global__ __launch_bounds__(256) void gemm_mfma(
    const AT* __restrict__ A, const float* __restrict__ A2,
    const unsigned short* __restrict__ Wb,
    const float* __restrict__ b1, const float* __restrict__ b2, int split,
    CT* __restrict__ C)
{
    constexpr int NT = NCOLS / 16;         // 16 or 6
    constexpr int JMAX = (NT + 3) / 4;     // 4 or 2
    constexpr int PITCH = 72;              // bf16 elems per LDS row (144 B)
    __shared__ __align__(16) unsigned short As[64 * PITCH];
    __shared__ __align__(16) unsigned short Bs[NCOLS * PITCH];

    const int t = threadIdx.x;
    const int wave = t >> 6, lane = t & 63;
    const int l15 = lane & 15, quad = lane >> 4;
    const size_t rowBase = (size_t)blockIdx.x * 64;

    f32x4 acc[4][JMAX];
#pragma unroll
    for (int m = 0; m < 4; ++m)
#pragma unroll
        for (int j = 0; j < JMAX; ++j) acc[m][j] = (f32x4){0.f, 0.f, 0.f, 0.f};

    for (int k0 = 0; k0 < 256; k0 += 64) {
        if (k0) __syncthreads();
        // ---- stage A: 64 rows x 64 k (512 groups of 8) ----
#pragma unroll
        for (int rep = 0; rep < 2; ++rep) {
            int f8 = t + 256 * rep;
            int row = f8 >> 3, g = f8 & 7;
            unsigned short* dst = &As[row * PITCH + g * 8];
            if constexpr (sizeof(AT) == 4) {
                const float* Ap = (const float*)A + (rowBase + row) * 256 + k0 + g * 8;
                float4 v0 = *(const float4*)Ap;
                float4 v1 = *(const float4*)(Ap + 4);
                if constexpr (HasA2) {
                    const float* Bp = A2 + (rowBase + row) * 256 + k0 + g * 8;
                    float4 w0 = *(const float4*)Bp;
                    float4 w1 = *(const float4*)(Bp + 4);
                    v0.x += w0.x; v0.y += w0.y; v0.z += w0.z; v0.w += w0.w;
                    v1.x += w1.x; v1.y += w1.y; v1.z += w1.z; v1.w += w1.w;
                }
                union { unsigned short u[8]; uint4 v; } tmp;
                tmp.u[0] = f2b(v0.x); tmp.u[1] = f2b(v0.y);
                tmp.u[2] = f2b(v0.z); tmp.u[3] = f2b(v0.w);
                tmp.u[4] = f2b(v1.x); tmp.u[5] = f2b(v1.y);
                tmp.u[6] = f2b(v1.z); tmp.u[7] = f2b(v1.w);
                *(uint4*)dst = tmp.v;
            } else {
                const unsigned short* Ap =
                    (const unsigned short*)A + (rowBase + row) * 256 + k0 + g * 8;
                *(uint4*)dst = *(const uint4*)Ap;
            }
        }
        // ---- stage B: NCOLS rows x 64 k (bf16 copy, L2-resident) ----
#pragma unroll
        for (int rep = 0; rep < NCOLS / 32; ++rep) {
            int f8 = t + 256 * rep;
            int row = f8 >> 3, g = f8 & 7;
            *(uint4*)&Bs[row * PITCH + g * 8] =
                *(const uint4*)&Wb[(size_t)row * 256 + k0 + g * 8];
        }
        __syncthreads();
        // ---- MFMA ----
#pragma unroll
        for (int ks = 0; ks < 2; ++ks) {
            s16x8 a[4], b[JMAX];
#pragma unroll
            for (int m = 0; m < 4; ++m)
                a[m] = *(const s16x8*)&As[(m * 16 + l15) * PITCH + ks * 32 + quad * 8];
#pragma unroll
            for (int j = 0; j < JMAX; ++j) {
                int tl = wave + 4 * j;
                if (tl < NT)
                    b[j] = *(const s16x8*)&Bs[(tl * 16 + l15) * PITCH + ks * 32 + quad * 8];
            }
#pragma unroll
            for (int m = 0; m < 4; ++m)
#pragma unroll
                for (int j = 0; j < JMAX; ++j)
                    if (wave + 4 * j < NT)
                        acc[m][j] = __builtin_amdgcn_mfma_f32_16x16x32_bf16(
                            a[m], b[j], acc[m][j], 0, 0, 0);
        }
    }

    // ---- epilogue ----
#pragma unroll
    for (int j = 0; j < JMAX; ++j) {
        int tl = wave + 4 * j;
        if (tl < NT) {
            int col = tl * 16 + l15;
            float bb = (col < split) ? b1[col] : b2[col - split];
#pragma unroll
            for (int m = 0; m < 4; ++m)
#pragma unroll
                for (int r2 = 0; r2 < 4; ++r2) {
                    size_t row = rowBase + m * 16 + quad * 4 + r2;
                    float v = acc[m][j][r2] + bb;
                    if constexpr (sizeof(CT) == 2)
                        C[row * NCOLS + col] = (CT)f2b(v);
                    else
                        C[row * NCOLS + col] = (CT)v;
                }
        }
    }
}

// ---------------------------------------------------------------------------
// Deformable sampling. Block = 256 thr, 8 queries per block.
// XCD-aware swizzle: XCD k (blockIdx%8) gets queries [k*5000,(k+1)*5000) --
// a 25-row BEV band whose value working set (~2.6 MB bf16) fits its 4 MB L2.
// Phase 1: thread (qi,h,p) -> fused corner weights + clamped indices in LDS.
// Phase 2: thread (h,d) -> 16 branchless bf16 gathers per query.
// ---------------------------------------------------------------------------
__global__ __launch_bounds__(256) void sample_kernel(
    const float* __restrict__ raw, const float* __restrict__ rp,
    const unsigned short* __restrict__ value, unsigned short* __restrict__ outa)
{
    __shared__ int4   sIdx[8][8][4];
    __shared__ float4 sW[8][8][4];

    const int b = blockIdx.x;
    const int qb = (b & 7) * 625 + (b >> 3);       // XCD swizzle (5000 = 8*625)
    const int t = threadIdx.x;
    {   // phase 1
        const int qi = t >> 5, h = (t >> 2) & 7, p = t & 3;
        const int q = qb * 8 + qi;
        const float* r = raw + (size_t)q * 96;
        float l0 = r[64 + h * 4 + 0], l1 = r[64 + h * 4 + 1];
        float l2 = r[64 + h * 4 + 2], l3 = r[64 + h * 4 + 3];
        float mx = fmaxf(fmaxf(l0, l1), fmaxf(l2, l3));
        float e0 = __expf(l0 - mx), e1 = __expf(l1 - mx);
        float e2 = __expf(l2 - mx), e3 = __expf(l3 - mx);
        float inv = 1.f / (e0 + e1 + e2 + e3);
        float ep = (p == 0) ? e0 : (p == 1) ? e1 : (p == 2) ? e2 : e3;
        float wp = ep * inv;

        float x = rp[(size_t)q * 2 + 0] * (float)WSP - 0.5f + r[h * 8 + p * 2 + 0];
        float y = rp[(size_t)q * 2 + 1] * (float)HSP - 0.5f + r[h * 8 + p * 2 + 1];
        float x0f = floorf(x), y0f = floorf(y);
        int x0 = (int)x0f, y0 = (int)y0f;
        float lw = x - x0f, lh = y - y0f;
        float cw[4] = {(1.f - lh) * (1.f - lw), (1.f - lh) * lw,
                       lh * (1.f - lw), lh * lw};
        int4 I; float4 W;
        int* Ip = &I.x; float* Wp = &W.x;
#pragma unroll
        for (int c = 0; c < 4; ++c) {
            int cx = x0 + (c & 1), cy = y0 + (c >> 1);
            bool valid = (cx >= 0) & (cx < WSP) & (cy >= 0) & (cy < HSP);
            int ccx = cx < 0 ? 0 : (cx > WSP - 1 ? WSP - 1 : cx);
            int ccy = cy < 0 ? 0 : (cy > HSP - 1 ? HSP - 1 : cy);
            Ip[c] = (ccy * WSP + ccx) * DMODEL + h * DHD;
            Wp[c] = valid ? cw[c] * wp : 0.f;
        }
        sIdx[qi][h][p] = I;
        sW[qi][h][p] = W;
    }
    __syncthreads();

    // phase 2
    const int h = t >> 5, d = t & 31;
    for (int qi = 0; qi < 8; ++qi) {
        float acc = 0.f;
#pragma unroll
        for (int p = 0; p < 4; ++p) {
            int4 I = sIdx[qi][h][p];
            float4 W = sW[qi][h][p];
            acc += W.x * b2f(value[I.x + d]);
            acc += W.y * b2f(value[I.y + d]);
            acc += W.z * b2f(value[I.z + d]);
            acc += W.w * b2f(value[I.w + d]);
        }
        int q = qb * 8 + qi;
        outa[(size_t)q * DMODEL + h * DHD + d] = f2b(acc);
    }
}

extern "C" void kernel_launch(void* const* d_in, const int* in_sizes, int n_in,
                              void* d_out, int out_size, void* d_ws, size_t ws_size,
                              hipStream_t stream)
{
    const float* query         = (const float*)d_in[0];
    const float* query_pos     = (const float*)d_in[1];
    const float* ref_points    = (const float*)d_in[2];
    const float* input_flatten = (const float*)d_in[3];
    const float* W_value       = (const float*)d_in[4];
    const float* b_value       = (const float*)d_in[5];
    const float* W_off         = (const float*)d_in[6];
    const float* b_off         = (const float*)d_in[7];
    const float* W_attn        = (const float*)d_in[8];
    const float* b_attn        = (const float*)d_in[9];
    const float* W_out         = (const float*)d_in[10];
    const float* b_out         = (const float*)d_in[11];
    float* out = (float*)d_out;

    unsigned short* val  = (unsigned short*)d_ws;                    // LQ*256 bf16
    float*          raw  = (float*)(val + (size_t)LQ * DMODEL);      // LQ*96 fp32
    unsigned short* outa = (unsigned short*)(raw + (size_t)LQ * 96); // LQ*256 bf16
    unsigned short* wbuf = outa + (size_t)LQ * DMODEL;               // 155648 bf16
    unsigned short* wv   = wbuf;
    unsigned short* woa  = wbuf + 65536;
    unsigned short* wout = wbuf + 90112;

    dim3 blk(256);

    // 0) weights -> bf16 (155648 elems, 4/thread)
    convert_weights<<<dim3(152), blk, 0, stream>>>(
        W_value, W_off, W_attn, W_out, wbuf);

    // 1) val(bf16) = input_flatten @ W_value^T + b_value
    gemm_mfma<256, float, unsigned short, false><<<dim3(LQ / 64), blk, 0, stream>>>(
        input_flatten, nullptr, wv, b_value, b_value, 256, val);

    // 2) raw = (query + query_pos) @ [W_off; W_attn]^T + [b_off; b_attn]
    gemm_mfma<96, float, float, true><<<dim3(LQ / 64), blk, 0, stream>>>(
        query, query_pos, woa, b_off, b_attn, 64, raw);

    // 3) softmax + bilinear sampling + point-weighted sum -> outa (bf16)
    sample_kernel<<<dim3(LQ / 8), blk, 0, stream>>>(raw, ref_points, val, outa);

    // 4) out = outa @ W_out^T + b_out
    gemm_mfma<256, unsigned short, float, false><<<dim3(LQ / 64), blk, 0, stream>>>(
        outa, nullptr, wout, b_out, b_out, 256, out);
}